// Round 4
// baseline (187.471 us; speedup 1.0000x reference)
//
#include <hip/hip_runtime.h>

// ROI max pooling, matching the JAX reference:
//   img:  (1, 200, 200, 512) fp32, NHWC
//   rois: (1, 128, 4) fp32 as (x, y, w, h) in feature-map pixels
//   pool: 7
// out: (1, 128, 7, 7, 512) fp32
//
// Bin boundaries replicate  int(x + k*(w/P))  in strict IEEE fp32
// (separate div/mul/add, no FMA contraction) so the integer pixel ranges
// match the reference exactly; the max over identical pixel sets is then
// bitwise identical.
//
// R6: locality WITHOUT the R5 overhead. R5 proved Morton+XCD chunking
// captures the cross-ROI reuse (FETCH 143->95 MB, image=82 MB) but lost
// time to (a) per-block O(128^2) sort (VALUBusy 8->36%) and (b) equal-
// count chunks with unequal area (slowest XCD ~+20%). Fix: a 1-block
// setup kernel builds the schedule ONCE into d_ws — Morton-rank the
// ROIs, cut the ranked list at equal-AREA octiles (contiguous chunks ->
// locality kept), map chunk items to that XCD's block slots (b%8=xcd),
// spill overflow to under-full XCDs in closed form. Main kernel: one
// uniform u16 table load. Bitwise-neutral: only block->(roi,bin)
// assignment changes.

#define IMG_H 200
#define IMG_W 200
#define IMG_C 512
#define C4 (IMG_C / 4)   // 128 float4 slots per pixel
#define POOL 7
#define NROI 128
#define PLANES 4         // pixel-lanes per block
#define NXCD 8
#define NBIN (POOL * POOL)
#define NITEM (NROI * NBIN)            // 6272
#define SLOTS_PER_XCD (NITEM / NXCD)   // 784

typedef float f4v __attribute__((ext_vector_type(4)));

__device__ __forceinline__ float4 max4(float4 a, float4 b) {
    return make_float4(fmaxf(a.x, b.x), fmaxf(a.y, b.y),
                       fmaxf(a.z, b.z), fmaxf(a.w, b.w));
}

__device__ __forceinline__ int imin(int a, int b) { return a < b ? a : b; }
__device__ __forceinline__ int imax(int a, int b) { return a > b ? a : b; }

// spread low 8 bits: b7..b0 -> 0b0b0b0b (Morton helper)
__device__ __forceinline__ unsigned spread8(unsigned x) {
    x &= 0xFFu;
    x = (x | (x << 4)) & 0x0F0Fu;
    x = (x | (x << 2)) & 0x3333u;
    x = (x | (x << 1)) & 0x5555u;
    return x;
}

// ---------------- setup: build balanced, Morton-local schedule ------------
// table[slot] = (roi<<6)|bin for slot = 0..6271; block b executes table[b].
// Hardware maps block b -> XCD b%8, so slot j*8+x belongs to XCD x.
__global__ __launch_bounds__(NROI) void build_schedule(
    const float* __restrict__ rois,
    unsigned short* __restrict__ table)
{
    __shared__ unsigned short key[NROI];
    __shared__ unsigned char  perm[NROI];      // Morton rank -> roi index
    __shared__ float          area[NROI];      // by Morton rank
    __shared__ float          pref[NROI + 1];  // area prefix (by rank)
    __shared__ int            chunk_of[NROI];  // rank -> xcd chunk (monotone)
    __shared__ int            rstart[NXCD];    // first rank of chunk
    __shared__ int            len[NXCD];       // #items (bins) in chunk
    __shared__ int            spillpre[NXCD + 1];
    __shared__ int            freepre[NXCD + 1];

    const int t = threadIdx.x;            // exactly NROI threads

    const float rx = rois[t * 4 + 0];
    const float ry = rois[t * 4 + 1];
    const float rw = rois[t * 4 + 2];
    const float rh = rois[t * 4 + 3];
    {
        const unsigned cx = (unsigned)(int)(rx + 0.5f * rw);   // 0..199
        const unsigned cy = (unsigned)(int)(ry + 0.5f * rh);
        key[t] = (unsigned short)((spread8(cy) << 1) | spread8(cx));
    }
    __syncthreads();

    // rank by (key, index) — bijective
    {
        const unsigned my = key[t];
        int r = 0;
        #pragma unroll 8
        for (int u = 0; u < NROI; ++u) {
            const unsigned ku = key[u];
            r += (int)((ku < my) | ((ku == my) & (u < t)));
        }
        perm[r] = (unsigned char)t;
        area[r] = rw * rh;
    }
    __syncthreads();

    if (t == 0) {
        // prefix areas over Morton order
        float s = 0.f;
        pref[0] = 0.f;
        for (int i = 0; i < NROI; ++i) { s += area[i]; pref[i + 1] = s; }
        const float inv = (float)NXCD / s;
        // equal-area cuts at ROI granularity, monotone chunk ids
        int prev = 0;
        for (int i = 0; i < NROI; ++i) {
            int c = (int)((pref[i] + 0.5f * area[i]) * inv);
            c = imin(c, NXCD - 1);
            c = imax(c, prev);
            prev = c;
            chunk_of[i] = c;
        }
        for (int x = 0; x < NXCD; ++x) { rstart[x] = 0; len[x] = 0; }
        for (int i = NROI - 1; i >= 0; --i) rstart[chunk_of[i]] = i;
        for (int i = 0; i < NROI; ++i) len[chunk_of[i]] += NBIN;
        // prefix of overflow items / free slots (equal totals by conservation)
        int sp = 0, fp = 0;
        for (int x = 0; x < NXCD; ++x) {
            spillpre[x] = sp;
            freepre[x]  = fp;
            sp += imax(0, len[x] - SLOTS_PER_XCD);
            fp += imax(0, SLOTS_PER_XCD - len[x]);
        }
        spillpre[NXCD] = sp;
        freepre[NXCD]  = fp;
    }
    __syncthreads();

    // each thread owns one Morton rank; emit its 49 items into slots
    const int x    = chunk_of[t];
    const int base = (t - rstart[x]) * NBIN;   // item offset within chunk
    const int roi  = (int)perm[t];
    for (int m = 0; m < NBIN; ++m) {
        const int j = base + m;
        const unsigned short e = (unsigned short)((roi << 6) | m);
        if (j < SLOTS_PER_XCD) {
            table[j * NXCD + x] = e;           // slot j*8+x -> XCD x
        } else {
            // spill: global spill index -> global free slot (closed form)
            const int si = spillpre[x] + (j - SLOTS_PER_XCD);
            int y = 0;
            while (!(si >= freepre[y] && si < freepre[y + 1])) ++y;
            const int fy = freepre[y + 1] - freepre[y];       // free slots in y
            const int k  = (SLOTS_PER_XCD - fy) + (si - freepre[y]);
            table[k * NXCD + y] = e;
        }
    }
}

// ---------------- main: ROI max pool --------------------------------------
__global__ __launch_bounds__(PLANES * 128, 8) void roi_pool_kernel(
    const float* __restrict__ img,
    const float* __restrict__ rois,
    const unsigned short* __restrict__ table,   // may be null -> identity
    float* __restrict__ out)
{
    int roi, bin;
    if (table) {
        const unsigned e = (unsigned)table[blockIdx.x];  // uniform -> s_load
        roi = (int)(e >> 6);
        bin = (int)(e & 63u);
    } else {
        roi = blockIdx.x / NBIN;
        bin = blockIdx.x % NBIN;
    }
    const int jy = bin / POOL;
    const int ix = bin % POOL;

    const float rx = rois[roi * 4 + 0];
    const float ry = rois[roi * 4 + 1];
    const float rw = rois[roi * 4 + 2];
    const float rh = rois[roi * 4 + 3];

    // Strict fp32, no contraction: s = w/P; b[k] = int(x + k*s)
    const float sx = __fdiv_rn(rw, 7.0f);
    const float sy = __fdiv_rn(rh, 7.0f);
    const int x1 = (int)__fadd_rn(rx, __fmul_rn((float)ix,       sx));
    const int x2 = (int)__fadd_rn(rx, __fmul_rn((float)(ix + 1), sx));
    const int y1 = (int)__fadd_rn(ry, __fmul_rn((float)jy,       sy));
    const int y2 = (int)__fadd_rn(ry, __fmul_rn((float)(jy + 1), sy));

    const int c4 = threadIdx.x & 127;       // channel quad
    const int p  = threadIdx.x >> 7;        // pixel-lane 0..3
    const float4* __restrict__ img4 = (const float4*)img;

    const int bw = x2 - x1;                 // >= 1 by problem construction
    const int area = bw * (y2 - y1);

    const float4 NEG = make_float4(-INFINITY, -INFINITY, -INFINITY, -INFINITY);
    float4 m = NEG;

    // Lane p handles linearized bin pixels p, p+4, p+8, ... (row-major in bin).
    int dx = p, dy = 0;
    while (dx >= bw) { dx -= bw; ++dy; }    // p<4, cheap init
    #pragma unroll 2
    for (int i = p; i < area; i += PLANES) {
        const size_t px = (size_t)(y1 + dy) * IMG_W + (size_t)(x1 + dx);
        m = max4(m, img4[px * C4 + c4]);
        dx += PLANES;
        while (dx >= bw) { dx -= bw; ++dy; }
    }

    // Cross-lane (p) reduction via LDS; lanes with no pixels hold -INF.
    __shared__ float4 red[PLANES - 1][C4];
    if (p > 0) red[p - 1][c4] = m;
    __syncthreads();
    if (p == 0) {
        m = max4(m, red[0][c4]);
        m = max4(m, red[1][c4]);
        m = max4(m, red[2][c4]);

        float4* __restrict__ out4 = (float4*)out;
        f4v* __restrict__ dst =
            (f4v*)&out4[((size_t)(roi * POOL + jy) * POOL + ix) * C4 + c4];
        __builtin_nontemporal_store(*(const f4v*)&m, dst);
    }
}

extern "C" void kernel_launch(void* const* d_in, const int* in_sizes, int n_in,
                              void* d_out, int out_size, void* d_ws, size_t ws_size,
                              hipStream_t stream) {
    (void)in_sizes; (void)n_in; (void)out_size;
    const float* img  = (const float*)d_in[0];
    const float* rois = (const float*)d_in[1];
    // d_in[2] is pool_size (=7), hardcoded.
    float* out = (float*)d_out;

    const bool use_table =
        (d_ws != nullptr) && (ws_size >= NITEM * sizeof(unsigned short));
    unsigned short* table = use_table ? (unsigned short*)d_ws : nullptr;

    if (use_table)
        build_schedule<<<dim3(1), dim3(NROI), 0, stream>>>(rois, table);

    roi_pool_kernel<<<dim3(NITEM), dim3(PLANES * 128), 0, stream>>>(
        img, rois, table, out);
}

// Round 5
// 184.781 us; speedup vs baseline: 1.0146x; 1.0146x over previous
//
#include <hip/hip_runtime.h>

// ROI max pooling, matching the JAX reference:
//   img:  (1, 200, 200, 512) fp32, NHWC
//   rois: (1, 128, 4) fp32 as (x, y, w, h) in feature-map pixels
//   pool: 7
// out: (1, 128, 7, 7, 512) fp32
//
// Bin boundaries replicate  int(x + k*(w/P))  in strict IEEE fp32
// (separate div/mul/add, no FMA contraction) so the integer pixel ranges
// match the reference exactly; the max over identical pixel sets is then
// bitwise identical.
//
// R7: R6 post-mortem — the Morton+equal-area schedule cut the main kernel
// 48 -> ~22us, but build_schedule's t==0 serial section (~400 dependent-
// LDS iterations) cost 73us. This version parallelizes the builder:
// Hillis-Steele area scan (7 steps), closed-form chunk ids (monotone by
// construction since pref_ex+0.5*area is strictly increasing), boundary-
// detect rstart, atomicAdd len. Only the 8-element spill/free prefix
// remains serial. Main kernel is byte-identical to R6's (proven correct,
// absmax 0.0).

#define IMG_H 200
#define IMG_W 200
#define IMG_C 512
#define C4 (IMG_C / 4)   // 128 float4 slots per pixel
#define POOL 7
#define NROI 128
#define PLANES 4         // pixel-lanes per block
#define NXCD 8
#define NBIN (POOL * POOL)
#define NITEM (NROI * NBIN)            // 6272
#define SLOTS_PER_XCD (NITEM / NXCD)   // 784

typedef float f4v __attribute__((ext_vector_type(4)));

__device__ __forceinline__ float4 max4(float4 a, float4 b) {
    return make_float4(fmaxf(a.x, b.x), fmaxf(a.y, b.y),
                       fmaxf(a.z, b.z), fmaxf(a.w, b.w));
}

__device__ __forceinline__ int imin(int a, int b) { return a < b ? a : b; }
__device__ __forceinline__ int imax(int a, int b) { return a > b ? a : b; }

// spread low 8 bits: b7..b0 -> 0b0b0b0b (Morton helper)
__device__ __forceinline__ unsigned spread8(unsigned x) {
    x &= 0xFFu;
    x = (x | (x << 4)) & 0x0F0Fu;
    x = (x | (x << 2)) & 0x3333u;
    x = (x | (x << 1)) & 0x5555u;
    return x;
}

// ---------------- setup: build balanced, Morton-local schedule ------------
// table[slot] = (roi<<6)|bin for slot = 0..6271; block b executes table[b].
// Hardware maps block b -> XCD b%8, so slot j*8+x belongs to XCD x.
__global__ __launch_bounds__(NROI) void build_schedule(
    const float* __restrict__ rois,
    unsigned short* __restrict__ table)
{
    __shared__ unsigned short key[NROI];
    __shared__ unsigned char  perm[NROI];      // Morton rank -> roi index
    __shared__ float          area[NROI];      // by Morton rank
    __shared__ float          pref[NROI];      // inclusive area scan (by rank)
    __shared__ int            chunk_of[NROI];  // rank -> xcd chunk (monotone)
    __shared__ int            rstart[NXCD];    // first rank of chunk
    __shared__ int            len[NXCD];       // #items (bins) in chunk
    __shared__ int            spillpre[NXCD + 1];
    __shared__ int            freepre[NXCD + 1];

    const int t = threadIdx.x;            // exactly NROI threads

    const float rx = rois[t * 4 + 0];
    const float ry = rois[t * 4 + 1];
    const float rw = rois[t * 4 + 2];
    const float rh = rois[t * 4 + 3];
    {
        const unsigned cx = (unsigned)(int)(rx + 0.5f * rw);   // 0..199
        const unsigned cy = (unsigned)(int)(ry + 0.5f * rh);
        key[t] = (unsigned short)((spread8(cy) << 1) | spread8(cx));
    }
    if (t < NXCD) len[t] = 0;
    __syncthreads();

    // rank by (key, index) — bijective; parallel across threads
    {
        const unsigned my = key[t];
        int r = 0;
        #pragma unroll 8
        for (int u = 0; u < NROI; ++u) {
            const unsigned ku = key[u];
            r += (int)((ku < my) | ((ku == my) & (u < t)));
        }
        perm[r] = (unsigned char)t;
        area[r] = rw * rh;
    }
    __syncthreads();

    // inclusive scan of area over Morton order (Hillis-Steele, 7 steps).
    // FP reassociation vs serial scan is harmless: cuts only affect
    // scheduling, never output bits.
    pref[t] = area[t];
    __syncthreads();
    #pragma unroll
    for (int d = 1; d < NROI; d <<= 1) {
        const float add = (t >= d) ? pref[t - d] : 0.f;
        __syncthreads();
        pref[t] += add;
        __syncthreads();
    }
    const float total = pref[NROI - 1];

    // equal-area chunk id; pref_ex + 0.5*area strictly increases with t,
    // so c is non-decreasing without any fixup.
    const float mid = pref[t] - 0.5f * area[t];
    const int c = imin((int)(mid * ((float)NXCD / total)), NXCD - 1);
    chunk_of[t] = c;
    atomicAdd(&len[c], NBIN);
    __syncthreads();
    if (t == 0 || chunk_of[t - 1] != c) rstart[c] = t;
    __syncthreads();

    if (t == 0) {
        // prefix of overflow items / free slots (equal totals by conservation)
        int sp = 0, fp = 0;
        #pragma unroll
        for (int x = 0; x < NXCD; ++x) {
            spillpre[x] = sp;
            freepre[x]  = fp;
            sp += imax(0, len[x] - SLOTS_PER_XCD);
            fp += imax(0, SLOTS_PER_XCD - len[x]);
        }
        spillpre[NXCD] = sp;
        freepre[NXCD]  = fp;
    }
    __syncthreads();

    // each thread owns one Morton rank; emit its 49 items into slots
    const int x    = chunk_of[t];
    const int base = (t - rstart[x]) * NBIN;   // item offset within chunk
    const int roi  = (int)perm[t];
    for (int m = 0; m < NBIN; ++m) {
        const int j = base + m;
        const unsigned short e = (unsigned short)((roi << 6) | m);
        if (j < SLOTS_PER_XCD) {
            table[j * NXCD + x] = e;           // slot j*8+x -> XCD x
        } else {
            // spill: global spill index -> global free slot (closed form)
            const int si = spillpre[x] + (j - SLOTS_PER_XCD);
            int y = 0;
            while (!(si >= freepre[y] && si < freepre[y + 1])) ++y;
            const int fy = freepre[y + 1] - freepre[y];       // free slots in y
            const int k  = (SLOTS_PER_XCD - fy) + (si - freepre[y]);
            table[k * NXCD + y] = e;
        }
    }
}

// ---------------- main: ROI max pool --------------------------------------
__global__ __launch_bounds__(PLANES * 128, 8) void roi_pool_kernel(
    const float* __restrict__ img,
    const float* __restrict__ rois,
    const unsigned short* __restrict__ table,   // may be null -> identity
    float* __restrict__ out)
{
    int roi, bin;
    if (table) {
        const unsigned e = (unsigned)table[blockIdx.x];  // uniform -> s_load
        roi = (int)(e >> 6);
        bin = (int)(e & 63u);
    } else {
        roi = blockIdx.x / NBIN;
        bin = blockIdx.x % NBIN;
    }
    const int jy = bin / POOL;
    const int ix = bin % POOL;

    const float rx = rois[roi * 4 + 0];
    const float ry = rois[roi * 4 + 1];
    const float rw = rois[roi * 4 + 2];
    const float rh = rois[roi * 4 + 3];

    // Strict fp32, no contraction: s = w/P; b[k] = int(x + k*s)
    const float sx = __fdiv_rn(rw, 7.0f);
    const float sy = __fdiv_rn(rh, 7.0f);
    const int x1 = (int)__fadd_rn(rx, __fmul_rn((float)ix,       sx));
    const int x2 = (int)__fadd_rn(rx, __fmul_rn((float)(ix + 1), sx));
    const int y1 = (int)__fadd_rn(ry, __fmul_rn((float)jy,       sy));
    const int y2 = (int)__fadd_rn(ry, __fmul_rn((float)(jy + 1), sy));

    const int c4 = threadIdx.x & 127;       // channel quad
    const int p  = threadIdx.x >> 7;        // pixel-lane 0..3
    const float4* __restrict__ img4 = (const float4*)img;

    const int bw = x2 - x1;                 // >= 1 by problem construction
    const int area = bw * (y2 - y1);

    const float4 NEG = make_float4(-INFINITY, -INFINITY, -INFINITY, -INFINITY);
    float4 m = NEG;

    // Lane p handles linearized bin pixels p, p+4, p+8, ... (row-major in bin).
    int dx = p, dy = 0;
    while (dx >= bw) { dx -= bw; ++dy; }    // p<4, cheap init
    #pragma unroll 2
    for (int i = p; i < area; i += PLANES) {
        const size_t px = (size_t)(y1 + dy) * IMG_W + (size_t)(x1 + dx);
        m = max4(m, img4[px * C4 + c4]);
        dx += PLANES;
        while (dx >= bw) { dx -= bw; ++dy; }
    }

    // Cross-lane (p) reduction via LDS; lanes with no pixels hold -INF.
    __shared__ float4 red[PLANES - 1][C4];
    if (p > 0) red[p - 1][c4] = m;
    __syncthreads();
    if (p == 0) {
        m = max4(m, red[0][c4]);
        m = max4(m, red[1][c4]);
        m = max4(m, red[2][c4]);

        float4* __restrict__ out4 = (float4*)out;
        f4v* __restrict__ dst =
            (f4v*)&out4[((size_t)(roi * POOL + jy) * POOL + ix) * C4 + c4];
        __builtin_nontemporal_store(*(const f4v*)&m, dst);
    }
}

extern "C" void kernel_launch(void* const* d_in, const int* in_sizes, int n_in,
                              void* d_out, int out_size, void* d_ws, size_t ws_size,
                              hipStream_t stream) {
    (void)in_sizes; (void)n_in; (void)out_size;
    const float* img  = (const float*)d_in[0];
    const float* rois = (const float*)d_in[1];
    // d_in[2] is pool_size (=7), hardcoded.
    float* out = (float*)d_out;

    const bool use_table =
        (d_ws != nullptr) && (ws_size >= NITEM * sizeof(unsigned short));
    unsigned short* table = use_table ? (unsigned short*)d_ws : nullptr;

    if (use_table)
        build_schedule<<<dim3(1), dim3(NROI), 0, stream>>>(rois, table);

    roi_pool_kernel<<<dim3(NITEM), dim3(PLANES * 128), 0, stream>>>(
        img, rois, table, out);
}

// Round 6
// 145.125 us; speedup vs baseline: 1.2918x; 1.2733x over previous
//
#include <hip/hip_runtime.h>

// ROI max pooling, matching the JAX reference:
//   img:  (1, 200, 200, 512) fp32, NHWC
//   rois: (1, 128, 4) fp32 as (x, y, w, h) in feature-map pixels
//   pool: 7
// out: (1, 128, 7, 7, 512) fp32
//
// Bin boundaries replicate  int(x + k*(w/P))  in strict IEEE fp32
// (separate div/mul/add, no FMA contraction) so the integer pixel ranges
// match the reference exactly; the max over identical pixel sets is then
// bitwise identical.
//
// R8: single-dispatch fold-in. R6/R7 proved (a) the Morton + equal-area
// XCD schedule cuts main-kernel time ~48 -> ~22-39us and FETCH 143->95MB,
// but (b) a separate builder dispatch has a ~50us floor (53us at
// VALUBusy 0.01%) that swamps the win. So each block now computes the
// schedule INVERSE at its own slot, in parallel, in ~1500 cycles:
//   - 4-way split Morton ranking (512 threads cover 128 ROIs x 128 keys)
//   - wave-shuffle area prefix scan (no Hillis-Steele barriers)
//   - equal-area chunk cuts, spill/free prefixes (8-iter serial tail)
//   - closed-form slot -> (roi,bin) inversion (direct + spill branches)
// All arithmetic is deterministic and identical across blocks (integer
// atomics only), so every block agrees on the same bijection ->
// bitwise-identical output, no workspace, no extra dispatch.

#define IMG_H 200
#define IMG_W 200
#define IMG_C 512
#define C4 (IMG_C / 4)   // 128 float4 slots per pixel
#define POOL 7
#define NROI 128
#define PLANES 4         // pixel-lanes per block
#define NXCD 8
#define NBIN (POOL * POOL)
#define NITEM (NROI * NBIN)            // 6272
#define SLOTS_PER_XCD (NITEM / NXCD)   // 784

typedef float f4v __attribute__((ext_vector_type(4)));

__device__ __forceinline__ float4 max4(float4 a, float4 b) {
    return make_float4(fmaxf(a.x, b.x), fmaxf(a.y, b.y),
                       fmaxf(a.z, b.z), fmaxf(a.w, b.w));
}

__device__ __forceinline__ int imin(int a, int b) { return a < b ? a : b; }
__device__ __forceinline__ int imax(int a, int b) { return a > b ? a : b; }

// spread low 8 bits: b7..b0 -> 0b0b0b0b (Morton helper)
__device__ __forceinline__ unsigned spread8(unsigned x) {
    x &= 0xFFu;
    x = (x | (x << 4)) & 0x0F0Fu;
    x = (x | (x << 2)) & 0x3333u;
    x = (x | (x << 1)) & 0x5555u;
    return x;
}

__global__ __launch_bounds__(PLANES * 128, 8) void roi_pool_kernel(
    const float* __restrict__ img,
    const float* __restrict__ rois,
    float* __restrict__ out)
{
    // ---- scheduling scratch (≈3.3 KB) + reduction buffer (6 KB) ----
    __shared__ unsigned short s_key[NROI];
    __shared__ float          s_areaROI[NROI];   // by roi index
    __shared__ int            s_rank[NROI];      // rank of roi t
    __shared__ unsigned char  s_perm[NROI];      // rank -> roi
    __shared__ float          s_area[NROI];      // by rank
    __shared__ float          s_pref[NROI];      // per-wave inclusive scan
    __shared__ int            s_chunk[NROI];     // rank -> xcd chunk
    __shared__ int            s_rstart[NXCD];
    __shared__ int            s_len[NXCD];
    __shared__ int            s_spillpre[NXCD + 1];
    __shared__ int            s_freepre[NXCD + 1];
    __shared__ int            s_roi, s_bin;
    __shared__ float4         red[PLANES - 1][C4];

    const int tid = threadIdx.x;
    const int t   = tid & 127;            // ROI / rank lane
    const int seg = tid >> 7;             // 0..3

    if (seg == 0) {
        const float rx = rois[t * 4 + 0];
        const float ry = rois[t * 4 + 1];
        const float rw = rois[t * 4 + 2];
        const float rh = rois[t * 4 + 3];
        const unsigned cx = (unsigned)(int)(rx + 0.5f * rw);   // 0..199
        const unsigned cy = (unsigned)(int)(ry + 0.5f * rh);
        s_key[t] = (unsigned short)((spread8(cy) << 1) | spread8(cx));
        s_areaROI[t] = rw * rh;
        s_rank[t] = 0;
    }
    if (tid < NXCD) s_len[tid] = 0;
    __syncthreads();                                           // B1

    // 4-way split ranking: tid ranks ROI t against keys [seg*32, seg*32+32)
    {
        const unsigned my = s_key[t];
        int r = 0;
        const int u0 = seg * 32;
        #pragma unroll 8
        for (int u = u0; u < u0 + 32; ++u) {
            const unsigned ku = s_key[u];
            r += (int)((ku < my) | ((ku == my) & (u < t)));
        }
        atomicAdd(&s_rank[t], r);
    }
    __syncthreads();                                           // B2

    if (seg == 0) {
        const int r = s_rank[t];
        s_perm[r] = (unsigned char)t;
        s_area[r] = s_areaROI[t];
    }
    __syncthreads();                                           // B3

    // inclusive area scan by rank: shuffle scan within each of 2 waves.
    if (seg == 0) {
        float v = s_area[t];
        #pragma unroll
        for (int d = 1; d < 64; d <<= 1) {
            const float o = __shfl_up(v, d);
            if ((t & 63) >= d) v += o;
        }
        s_pref[t] = v;                     // wave-local inclusive
    }
    __syncthreads();                                           // B4

    if (seg == 0) {
        const float w0tot = s_pref[63];
        const float pre   = s_pref[t] + ((t >= 64) ? w0tot : 0.f);
        const float total = s_pref[127] + w0tot;
        // equal-area chunk id at ROI midpoint; monotone in t by construction
        const float mid = pre - 0.5f * s_area[t];
        const int c = imin((int)(mid * ((float)NXCD / total)), NXCD - 1);
        s_chunk[t] = c;
        atomicAdd(&s_len[c], NBIN);
    }
    __syncthreads();                                           // B5

    if (seg == 0) {
        const int c = s_chunk[t];
        if (t == 0 || s_chunk[t - 1] != c) s_rstart[c] = t;
    }
    if (tid == 0) {
        int sp = 0, fp = 0;
        #pragma unroll
        for (int x = 0; x < NXCD; ++x) {
            s_spillpre[x] = sp;
            s_freepre[x]  = fp;
            sp += imax(0, s_len[x] - SLOTS_PER_XCD);
            fp += imax(0, SLOTS_PER_XCD - s_len[x]);
        }
        s_spillpre[NXCD] = sp;
        s_freepre[NXCD]  = fp;
    }
    __syncthreads();                                           // B6

    // closed-form inverse: slot blockIdx.x -> (roi, bin).
    // Forward (R6): rank tt in chunk x emits items j=(tt-rstart[x])*49+m;
    // j<784 -> slot j*8+x; overflow si=spillpre[x]+(j-784) fills the si-th
    // global free slot: XCD y with freepre[y]<=si<freepre[y+1], at
    // k = len[y] + (si - freepre[y]).
    if (tid == 0) {
        const int x = blockIdx.x & (NXCD - 1);
        const int j = blockIdx.x >> 3;
        int tt, mm;
        if (j < s_len[x]) {                 // direct item of chunk x
            tt = s_rstart[x] + j / NBIN;
            mm = j % NBIN;
        } else {                            // filled free slot
            const int si = s_freepre[x] + (j - s_len[x]);
            int xx = 0;
            while (!(si >= s_spillpre[xx] && si < s_spillpre[xx + 1])) ++xx;
            const int jj = SLOTS_PER_XCD + (si - s_spillpre[xx]);
            tt = s_rstart[xx] + jj / NBIN;
            mm = jj % NBIN;
        }
        s_roi = (int)s_perm[tt];
        s_bin = mm;
    }
    __syncthreads();                                           // B7

    const int roi = s_roi;
    const int bin = s_bin;
    const int jy = bin / POOL;
    const int ix = bin % POOL;

    const float rx = rois[roi * 4 + 0];
    const float ry = rois[roi * 4 + 1];
    const float rw = rois[roi * 4 + 2];
    const float rh = rois[roi * 4 + 3];

    // Strict fp32, no contraction: s = w/P; b[k] = int(x + k*s)
    const float sx = __fdiv_rn(rw, 7.0f);
    const float sy = __fdiv_rn(rh, 7.0f);
    const int x1 = (int)__fadd_rn(rx, __fmul_rn((float)ix,       sx));
    const int x2 = (int)__fadd_rn(rx, __fmul_rn((float)(ix + 1), sx));
    const int y1 = (int)__fadd_rn(ry, __fmul_rn((float)jy,       sy));
    const int y2 = (int)__fadd_rn(ry, __fmul_rn((float)(jy + 1), sy));

    const int c4 = tid & 127;               // channel quad
    const int p  = tid >> 7;                // pixel-lane 0..3
    const float4* __restrict__ img4 = (const float4*)img;

    const int bw = x2 - x1;                 // >= 1 by problem construction
    const int area = bw * (y2 - y1);

    const float4 NEG = make_float4(-INFINITY, -INFINITY, -INFINITY, -INFINITY);
    float4 m = NEG;

    // Lane p handles linearized bin pixels p, p+4, p+8, ... (row-major in bin).
    int dx = p, dy = 0;
    while (dx >= bw) { dx -= bw; ++dy; }    // p<4, cheap init
    #pragma unroll 2
    for (int i = p; i < area; i += PLANES) {
        const size_t px = (size_t)(y1 + dy) * IMG_W + (size_t)(x1 + dx);
        m = max4(m, img4[px * C4 + c4]);
        dx += PLANES;
        while (dx >= bw) { dx -= bw; ++dy; }
    }

    // Cross-lane (p) reduction via LDS; lanes with no pixels hold -INF.
    if (p > 0) red[p - 1][c4] = m;
    __syncthreads();                                           // B8
    if (p == 0) {
        m = max4(m, red[0][c4]);
        m = max4(m, red[1][c4]);
        m = max4(m, red[2][c4]);

        float4* __restrict__ out4 = (float4*)out;
        f4v* __restrict__ dst =
            (f4v*)&out4[((size_t)(roi * POOL + jy) * POOL + ix) * C4 + c4];
        __builtin_nontemporal_store(*(const f4v*)&m, dst);
    }
}

extern "C" void kernel_launch(void* const* d_in, const int* in_sizes, int n_in,
                              void* d_out, int out_size, void* d_ws, size_t ws_size,
                              hipStream_t stream) {
    (void)in_sizes; (void)n_in; (void)d_ws; (void)ws_size; (void)out_size;
    const float* img  = (const float*)d_in[0];
    const float* rois = (const float*)d_in[1];
    // d_in[2] is pool_size (=7), hardcoded.
    float* out = (float*)d_out;

    roi_pool_kernel<<<dim3(NITEM), dim3(PLANES * 128), 0, stream>>>(
        img, rois, out);
}